// Round 8
// baseline (162.604 us; speedup 1.0000x reference)
//
#include <hip/hip_runtime.h>

// B=4, N=2048, C=256, ic=128.  Algebra (rounds 1-7 validated the S-path):
//   T=lin(aim,th) P=lin(detect,ph) Gd=lin(detect,g) Ga=lin(aim,g2)   [bf16]
//   X_v := per-batch view [128,4096] of [2048,256] (pure reshape)
//   S_aT = Gd_v @ P_v^T ; S_bT = Ga_v @ T_v^T        [128,128]
// Round 8 NEW: weight composition kills the second output GEMM:
//   out_aim_v = S_aT/4096 @ Za_v + W_b + aim,  Za = lin(aim, W_w@th_w, W_w@th_b)
//   out_det_v = S_bT/4096 @ Zd_v + Q_b + det,  Zd = lin(detect, Q_w@ph_w, Q_w@ph_b)
// (proof: (NA@W^T)_v = S/4096 @ (T@W^T)_v and T@W^T composes into one linear.)
// R7 post-mortem: all kernels latency-bound at 1 block/CU (LDS 30-38 KB).
// Fix: every GEMM <=16 KB LDS, __launch_bounds__(256,4), 512-1536-block grids.

typedef __attribute__((ext_vector_type(4))) float  f32x4;
typedef __attribute__((ext_vector_type(8))) __bf16 bf16x8;
typedef __attribute__((ext_vector_type(8))) unsigned short u16x8;
typedef __attribute__((ext_vector_type(4))) unsigned short u16x4;

__device__ inline unsigned short f2bf(float f) {
    union { float f; unsigned u; } c; c.f = f;
    unsigned r = c.u + 0x7FFF + ((c.u >> 16) & 1);   // RNE
    return (unsigned short)(r >> 16);
}
__device__ inline bf16x8 ldfrag(const unsigned short* p) {
    return __builtin_bit_cast(bf16x8, *(const u16x8*)p);
}

struct Params {
    const float *detect, *aim;
    const float *g_w, *g2_w, *th_w, *ph_w, *W_w, *Q_w;
    const float *g_b, *g2_b, *th_b, *ph_b, *W_b, *Q_b;
    unsigned short *Wall;                 // [6][65536] bf16: th,g2,Wc_a,ph,g,Wc_d
    unsigned short *Abf, *Dbf;            // aim/detect bf16
    unsigned short *T, *Ga, *Za, *P, *Gd, *Zd;   // [4][2048][256] bf16
    unsigned short *S;                    // [2][4][128][128] bf16
    float *Spart;                         // [2][4][16][128][128] fp32
    float *bc;                            // [2][256] composed biases
    float *out_det, *out_aim;
};

// ---------------- K0: weight compose + all fp32->bf16 conversions ------------
// grid 96: blocks 0-31 compose (16 rows each), 32-95 grid-stride convert.
__global__ __launch_bounds__(256)
void wcomp_kernel(Params p)
{
    const int bx = blockIdx.x, tid = threadIdx.x;
    if (bx < 32) {
        const int comp = bx >> 4, r0 = (bx & 15) * 16;
        const float* Wbig = comp ? p.Q_w : p.W_w;
        const float* Th   = comp ? p.ph_w : p.th_w;
        const float* tb   = comp ? p.ph_b : p.th_b;
        unsigned short* out = p.Wall + (size_t)(comp ? 5 : 2) * 65536;
        float* bco = p.bc + comp * 256;

        __shared__ float Wl[16][257];
        __shared__ float red[16][17];
        #pragma unroll
        for (int i = 0; i < 16; ++i)
            Wl[i][tid] = Wbig[(size_t)(r0 + i) * 256 + tid];
        __syncthreads();

        float acc[16] = {};
        for (int c = 0; c < 256; ++c) {
            float th = Th[(size_t)c * 256 + tid];
            #pragma unroll
            for (int i = 0; i < 16; ++i) acc[i] += Wl[i][c] * th;
        }
        #pragma unroll
        for (int i = 0; i < 16; ++i)
            out[(size_t)(r0 + i) * 256 + tid] = f2bf(acc[i]);

        {   // composed bias rows r0..r0+15
            int i = tid >> 4, c0 = (tid & 15) * 16;
            float s = 0.f;
            #pragma unroll
            for (int c = 0; c < 16; ++c) s += Wl[i][c0 + c] * tb[c0 + c];
            red[i][tid & 15] = s;
        }
        __syncthreads();
        if (tid < 16) {
            float s = 0.f;
            #pragma unroll
            for (int j = 0; j < 16; ++j) s += red[tid][j];
            bco[r0 + tid] = s;
        }
    } else {
        // convert: aim 524288 f4 | detect 524288 | th 16384 | g2 | ph | g
        const size_t stride = 64 * 256;
        for (size_t t = (size_t)(bx - 32) * 256 + tid; t < 1114112; t += stride) {
            const float* src; unsigned short* dst; size_t off;
            if (t < 524288)       { src = p.aim;    dst = p.Abf;              off = t; }
            else if (t < 1048576) { src = p.detect; dst = p.Dbf;              off = t - 524288; }
            else if (t < 1064960) { src = p.th_w;   dst = p.Wall;             off = t - 1048576; }
            else if (t < 1081344) { src = p.g2_w;   dst = p.Wall + 65536;     off = t - 1064960; }
            else if (t < 1097728) { src = p.ph_w;   dst = p.Wall + 3 * 65536; off = t - 1081344; }
            else                  { src = p.g_w;    dst = p.Wall + 4 * 65536; off = t - 1097728; }
            float4 v = ((const float4*)src)[off];
            u16x4 pk; pk[0]=f2bf(v.x); pk[1]=f2bf(v.y); pk[2]=f2bf(v.z); pk[3]=f2bf(v.w);
            ((u16x4*)dst)[off] = pk;
        }
    }
}

// ---------------- K1: six linears, all-bf16, tile 64x128, 4 blocks/CU --------
// grid (2,128,6): x=n-tile, y=m-tile, z=combo {T,Ga,Za | P,Gd,Zd}.
__global__ __launch_bounds__(256, 4)
void linall6_kernel(Params p)
{
    const int combo = blockIdx.z;
    const unsigned short* A = combo < 3 ? p.Abf : p.Dbf;
    const unsigned short* Wm = p.Wall + (size_t)combo * 65536;
    const float* Bv; unsigned short* O;
    switch (combo) {
        case 0:  Bv = p.th_b;     O = p.T;  break;
        case 1:  Bv = p.g2_b;     O = p.Ga; break;
        case 2:  Bv = p.bc;       O = p.Za; break;
        case 3:  Bv = p.ph_b;     O = p.P;  break;
        case 4:  Bv = p.g_b;      O = p.Gd; break;
        default: Bv = p.bc + 256; O = p.Zd; break;
    }
    const int m0 = blockIdx.y * 64, n0 = blockIdx.x * 128;

    __shared__ unsigned short As[64][40];    // 5.1 KB
    __shared__ unsigned short Bs[128][40];   // 10.2 KB

    const int tid = threadIdx.x, lane = tid & 63, w = tid >> 6;
    const int wr = w >> 1, wc = w & 1, q = lane >> 4, ln = lane & 15;

    f32x4 acc[2][4] = {};

    for (int k0 = 0; k0 < 256; k0 += 32) {
        {                                        // A: 64x32 = 256 u16x8
            int row = tid >> 2, c8 = tid & 3;
            *(u16x8*)&As[row][c8 * 8] = *(const u16x8*)(A + (size_t)(m0 + row) * 256 + k0 + c8 * 8);
        }
        #pragma unroll
        for (int i = 0; i < 2; ++i) {            // W: 128x32 = 512 u16x8
            int c = tid + i * 256, row = c >> 2, c8 = c & 3;
            *(u16x8*)&Bs[row][c8 * 8] = *(const u16x8*)(Wm + (size_t)(n0 + row) * 256 + k0 + c8 * 8);
        }
        __syncthreads();
        bf16x8 af[2], bb[4];
        #pragma unroll
        for (int i = 0; i < 2; ++i) af[i] = ldfrag(&As[wr * 32 + i * 16 + ln][q * 8]);
        #pragma unroll
        for (int j = 0; j < 4; ++j) bb[j] = ldfrag(&Bs[wc * 64 + j * 16 + ln][q * 8]);
        #pragma unroll
        for (int i = 0; i < 2; ++i)
            #pragma unroll
            for (int j = 0; j < 4; ++j)
                acc[i][j] = __builtin_amdgcn_mfma_f32_16x16x32_bf16(af[i], bb[j], acc[i][j], 0, 0, 0);
        __syncthreads();
    }

    #pragma unroll
    for (int i = 0; i < 2; ++i)
        #pragma unroll
        for (int j = 0; j < 4; ++j) {
            int n = n0 + wc * 64 + j * 16 + ln;
            float bias = Bv[n];
            #pragma unroll
            for (int r = 0; r < 4; ++r) {
                int m = m0 + wr * 32 + i * 16 + q * 4 + r;
                O[(size_t)m * 256 + n] = f2bf(acc[i][j][r] + bias);
            }
        }
}

// ---------------- K2: S partials, tile 64x64, 10.2 KB, all-resident ----------
// grid 512: which(1b) batch(2b) ms(1b) ns(1b) chunk(4b). KC=256, BK=32.
__global__ __launch_bounds__(256, 4)
void spart_kernel(Params p)
{
    const int bx = blockIdx.x, tid = threadIdx.x;
    const int which = bx >> 8, batch = (bx >> 6) & 3;
    const int ms = (bx >> 5) & 1, ns = (bx >> 4) & 1, chunk = bx & 15;
    const unsigned short* A = (which ? p.Ga : p.Gd) + (size_t)batch * 524288;
    const unsigned short* B = (which ? p.T  : p.P ) + (size_t)batch * 524288;
    float* Sp = p.Spart + ((size_t)(which * 4 + batch) * 16 + chunk) * 16384;
    const int kbeg = chunk * 256;

    __shared__ unsigned short As[64][40], Bs[64][40];
    const int lane = tid & 63, w = tid >> 6;
    const int wr = w >> 1, wc = w & 1, q = lane >> 4, ln = lane & 15;

    f32x4 acc[2][2] = {};

    for (int k0 = kbeg; k0 < kbeg + 256; k0 += 32) {
        {                                        // A,B: 64x32 = 256 u16x8 each
            int row = tid >> 2, c8 = tid & 3;
            *(u16x8*)&As[row][c8 * 8] =
                *(const u16x8*)(A + (size_t)(ms * 64 + row) * 4096 + k0 + c8 * 8);
            *(u16x8*)&Bs[row][c8 * 8] =
                *(const u16x8*)(B + (size_t)(ns * 64 + row) * 4096 + k0 + c8 * 8);
        }
        __syncthreads();
        bf16x8 af[2], bb[2];
        #pragma unroll
        for (int i = 0; i < 2; ++i) af[i] = ldfrag(&As[wr * 32 + i * 16 + ln][q * 8]);
        #pragma unroll
        for (int j = 0; j < 2; ++j) bb[j] = ldfrag(&Bs[wc * 32 + j * 16 + ln][q * 8]);
        #pragma unroll
        for (int i = 0; i < 2; ++i)
            #pragma unroll
            for (int j = 0; j < 2; ++j)
                acc[i][j] = __builtin_amdgcn_mfma_f32_16x16x32_bf16(af[i], bb[j], acc[i][j], 0, 0, 0);
        __syncthreads();
    }

    #pragma unroll
    for (int i = 0; i < 2; ++i)
        #pragma unroll
        for (int j = 0; j < 2; ++j)
            #pragma unroll
            for (int r = 0; r < 4; ++r) {
                int m = ms * 64 + wr * 32 + i * 16 + q * 4 + r;
                int n = ns * 64 + wc * 32 + j * 16 + ln;
                Sp[m * 128 + n] = acc[i][j][r];
            }
}

// ---------------- K3: reduce 16 partials -> bf16 S ---------------------------
// grid 128: 32768 float4 tasks.
__global__ __launch_bounds__(256)
void sred_kernel(Params p)
{
    const int fi = blockIdx.x * 256 + threadIdx.x;
    const int g = fi >> 12, e4 = fi & 4095;
    const float* base = p.Spart + (size_t)g * 16 * 16384 + (size_t)e4 * 4;
    f32x4 s = {};
    #pragma unroll
    for (int c = 0; c < 16; ++c) s += *(const f32x4*)(base + (size_t)c * 16384);
    u16x4 pk; pk[0]=f2bf(s[0]); pk[1]=f2bf(s[1]); pk[2]=f2bf(s[2]); pk[3]=f2bf(s[3]);
    *(u16x4*)(p.S + (size_t)g * 16384 + e4 * 4) = pk;
}

// ---------------- K4: out_v = S/4096 @ Z_v + bias + residual -----------------
// grid 1024: which(1b) batch(2b) mt(2b) nt4(5b). Tile 32(M)x128(N), K=128.
// S A-frags preloaded from L2 into registers (no S LDS tile): LDS = Zs only.
__global__ __launch_bounds__(256, 4)
void outgemm_kernel(Params p)
{
    const int bx = blockIdx.x, tid = threadIdx.x;
    const int lane = tid & 63, w = tid >> 6;
    const int q = lane >> 4, ln = lane & 15;

    const int which = bx >> 9, batch = (bx >> 7) & 3, mt = (bx >> 5) & 3, nt4 = bx & 31;
    const int m0 = mt * 32, n0 = nt4 * 128;
    const unsigned short* Sg = p.S + (size_t)(which * 4 + batch) * 16384 + (size_t)m0 * 128;
    const unsigned short* Z = (which ? p.Zd : p.Za) + (size_t)batch * 524288;
    const float* Bv = which ? p.Q_b : p.W_b;
    const float* R  = which ? p.detect : p.aim;
    float* O = which ? p.out_det : p.out_aim;
    const int s = n0 >> 8, cbase = n0 & 255;

    __shared__ unsigned short Zs[32][136];   // 8.7 KB, natural [k][j]

    // preload all A-frags: af[kc][mi], rows mi*16+ln, k = kc*32 + q*8 .. +8
    bf16x8 af[4][2];
    #pragma unroll
    for (int kc = 0; kc < 4; ++kc)
        #pragma unroll
        for (int mi = 0; mi < 2; ++mi)
            af[kc][mi] = ldfrag(Sg + (size_t)(mi * 16 + ln) * 128 + kc * 32 + q * 8);

    f32x4 acc[2][2] = {};
    for (int kc = 0; kc < 4; ++kc) {
        #pragma unroll
        for (int it = 0; it < 2; ++it) {         // Zs: 32k x 128j = 512 u16x8
            int c = tid + it * 256, kk = c >> 4, j8 = c & 15;
            *(u16x8*)&Zs[kk][j8 * 8] =
                *(const u16x8*)(Z + (size_t)(kc * 32 + kk) * 4096 + n0 + j8 * 8);
        }
        __syncthreads();
        #pragma unroll
        for (int ntl = 0; ntl < 2; ++ntl) {
            int col = w * 32 + ntl * 16 + ln;
            u16x8 t;
            #pragma unroll
            for (int i = 0; i < 8; ++i) t[i] = Zs[q * 8 + i][col];
            bf16x8 bb = __builtin_bit_cast(bf16x8, t);
            #pragma unroll
            for (int mi = 0; mi < 2; ++mi)
                acc[mi][ntl] = __builtin_amdgcn_mfma_f32_16x16x32_bf16(af[kc][mi], bb, acc[mi][ntl], 0, 0, 0);
        }
        __syncthreads();
    }

    #pragma unroll
    for (int mi = 0; mi < 2; ++mi)
        #pragma unroll
        for (int ntl = 0; ntl < 2; ++ntl) {
            int jl = w * 32 + ntl * 16 + ln;
            int c = cbase + jl;
            float bias = Bv[c];
            #pragma unroll
            for (int r = 0; r < 4; ++r) {
                int mv = m0 + mi * 16 + q * 4 + r;        // view row [0,128)
                int row = mv * 16 + s;                    // tensor row [0,2048)
                size_t idx = ((size_t)batch * 2048 + row) * 256 + c;
                O[idx] = acc[mi][ntl][r] * (1.0f / 4096.0f) + bias + R[idx];
            }
        }
}

extern "C" void kernel_launch(void* const* d_in, const int* in_sizes, int n_in,
                              void* d_out, int out_size, void* d_ws, size_t ws_size,
                              hipStream_t stream)
{
    Params p;
    p.detect = (const float*)d_in[0];
    p.aim    = (const float*)d_in[1];
    p.g_w  = (const float*)d_in[2];  p.g_b  = (const float*)d_in[3];
    p.g2_w = (const float*)d_in[4];  p.g2_b = (const float*)d_in[5];
    p.th_w = (const float*)d_in[6];  p.th_b = (const float*)d_in[7];
    p.ph_w = (const float*)d_in[8];  p.ph_b = (const float*)d_in[9];
    p.W_w  = (const float*)d_in[10]; p.W_b  = (const float*)d_in[11];
    p.Q_w  = (const float*)d_in[12]; p.Q_b  = (const float*)d_in[13];

    const size_t TOT = 8192L * 256;   // 2,097,152

    unsigned short* ws16 = (unsigned short*)d_ws;
    p.Wall = ws16;                       // [6][65536]
    p.Abf  = p.Wall + 6 * 65536;
    p.Dbf  = p.Abf + TOT;
    p.T    = p.Dbf + TOT;
    p.Ga   = p.T  + TOT;
    p.Za   = p.Ga + TOT;
    p.P    = p.Za + TOT;
    p.Gd   = p.P  + TOT;
    p.Zd   = p.Gd + TOT;
    p.S    = p.Zd + TOT;                 // [8][16384] bf16
    p.Spart = (float*)(p.S + 8 * 16384); // [8][16][16384] fp32 = 8.4 MB
    p.bc    = p.Spart + 8 * 16 * 16384;  // [2][256] fp32

    p.out_det = (float*)d_out;
    p.out_aim = p.out_det + TOT;

    wcomp_kernel  <<<96, 256, 0, stream>>>(p);
    linall6_kernel<<<dim3(2, 128, 6), 256, 0, stream>>>(p);
    spart_kernel  <<<512, 256, 0, stream>>>(p);
    sred_kernel   <<<128, 256, 0, stream>>>(p);
    outgemm_kernel<<<1024, 256, 0, stream>>>(p);
}